// Round 1
// baseline (263.019 us; speedup 1.0000x reference)
//
#include <hip/hip_runtime.h>

#define NB 16
#define NS 1024
#define NHID 64
#define NHEADS 4
#define NDH 16
#define LN_EPS 1e-5f

// ---------------------------------------------------------------------------
// Kernel 1: QKV projection. x[b,s,:] @ W^T + b  -> q/k/v in [B,NH,S,DH] layout.
// One block = 32 rows of x. W's staged transposed in LDS (pad 65 -> conflict-free).
// ---------------------------------------------------------------------------
__global__ __launch_bounds__(256) void qkv_kernel(
    const float* __restrict__ x,
    const float* __restrict__ Wq, const float* __restrict__ bq,
    const float* __restrict__ Wk, const float* __restrict__ bk,
    const float* __restrict__ Wv, const float* __restrict__ bv,
    float* __restrict__ qo, float* __restrict__ ko, float* __restrict__ vo)
{
    __shared__ float wqt[64][65], wkt[64][65], wvt[64][65];
    __shared__ float xs[32][64];
    int t = threadIdx.x;
    int row0 = blockIdx.x * 32;          // global row index (b*NS + s)
    for (int i = t; i < 4096; i += 256) {
        int c = i >> 6, j = i & 63;      // W[c][j] -> WT[j][c]
        wqt[j][c] = Wq[i];
        wkt[j][c] = Wk[i];
        wvt[j][c] = Wv[i];
    }
    for (int i = t; i < 2048; i += 256) {
        xs[i >> 6][i & 63] = x[(size_t)row0 * 64 + i];
    }
    __syncthreads();
    int c = t & 63, rq = t >> 6;
    int h = c >> 4, d = c & 15;
    float bqv = bq[c], bkv = bk[c], bvv = bv[c];
    for (int rr = 0; rr < 8; ++rr) {
        int r = rq * 8 + rr;
        float aq = bqv, ak = bkv, av = bvv;
        #pragma unroll
        for (int j = 0; j < 64; ++j) {
            float xv = xs[r][j];                 // wave-broadcast
            aq = fmaf(xv, wqt[j][c], aq);        // stride-1 across lanes
            ak = fmaf(xv, wkt[j][c], ak);
            av = fmaf(xv, wvt[j][c], av);
        }
        int srow = row0 + r;
        int b_ = srow >> 10, s_ = srow & 1023;
        size_t o = (((size_t)(b_ * NHEADS + h)) * NS + s_) * NDH + d;
        qo[o] = aq; ko[o] = ak; vo[o] = av;
    }
}

// ---------------------------------------------------------------------------
// Kernel 2: attention. One block per (b, q-row), all 4 heads.
// scores in LDS [4][1024]; per-wave-per-head softmax; writes atten_mean;
// accumulates out = att @ v into [B,S,64].
// ---------------------------------------------------------------------------
__device__ __forceinline__ float dot16(const float4* __restrict__ kp,
                                       const float* __restrict__ qh) {
    float4 a = kp[0], b = kp[1], c = kp[2], d = kp[3];
    return a.x*qh[0] + a.y*qh[1] + a.z*qh[2] + a.w*qh[3]
         + b.x*qh[4] + b.y*qh[5] + b.z*qh[6] + b.w*qh[7]
         + c.x*qh[8] + c.y*qh[9] + c.z*qh[10] + c.w*qh[11]
         + d.x*qh[12] + d.y*qh[13] + d.z*qh[14] + d.w*qh[15];
}

__global__ __launch_bounds__(256) void attn_kernel(
    const float* __restrict__ q, const float* __restrict__ k,
    const float* __restrict__ v, const int* __restrict__ lengths,
    float* __restrict__ amean,   // [B,S,S]
    float* __restrict__ out)     // [B,S,64]
{
    __shared__ float sc[NHEADS][NS];
    __shared__ float qsh[NHEADS][NDH];
    __shared__ float redm[NHEADS], redi[NHEADS];
    __shared__ float po[4][64];
    int t = threadIdx.x;
    int qrow = blockIdx.x;
    int b = blockIdx.y;
    int len = lengths[b];
    int klim = (qrow < len) ? min(qrow + 1, len) : 0;

    if (t < 64) {
        int h = t >> 4, d = t & 15;
        qsh[h][d] = q[(((size_t)(b * NHEADS + h)) * NS + qrow) * NDH + d];
    }
    __syncthreads();

    // scores (scaled by 1/sqrt(64) = 0.125)
    #pragma unroll
    for (int i = 0; i < 4; ++i) {
        int kk = t + 256 * i;
        if (kk < klim) {
            #pragma unroll
            for (int h = 0; h < 4; ++h) {
                const float4* kph =
                    (const float4*)&k[(((size_t)(b * NHEADS + h)) * NS + kk) * NDH];
                sc[h][kk] = dot16(kph, qsh[h]) * 0.125f;
            }
        } else {
            sc[0][kk] = -1e30f; sc[1][kk] = -1e30f;
            sc[2][kk] = -1e30f; sc[3][kk] = -1e30f;
        }
    }
    __syncthreads();

    // per-head softmax stats: wave w handles head w
    {
        int wv = t >> 6, ln = t & 63;
        float m = -1e30f;
        #pragma unroll
        for (int i = 0; i < 16; ++i) m = fmaxf(m, sc[wv][ln + 64 * i]);
        #pragma unroll
        for (int o = 32; o > 0; o >>= 1) m = fmaxf(m, __shfl_xor(m, o, 64));
        float ssum = 0.f;
        #pragma unroll
        for (int i = 0; i < 16; ++i) {
            float sv = sc[wv][ln + 64 * i];
            ssum += (sv > -1e29f) ? __expf(sv - m) : 0.f;
        }
        #pragma unroll
        for (int o = 32; o > 0; o >>= 1) ssum += __shfl_xor(ssum, o, 64);
        if (ln == 0) {
            redm[wv] = m;
            redi[wv] = (klim > 0) ? 1.f / ssum : 0.f;
        }
    }
    __syncthreads();

    float m0 = redm[0], m1 = redm[1], m2 = redm[2], m3 = redm[3];
    float i0 = redi[0], i1 = redi[1], i2 = redi[2], i3 = redi[3];
    #pragma unroll
    for (int i = 0; i < 4; ++i) {
        int kk = t + 256 * i;
        bool val = kk < klim;
        float a0 = val ? __expf(sc[0][kk] - m0) * i0 : 0.f;
        float a1 = val ? __expf(sc[1][kk] - m1) * i1 : 0.f;
        float a2 = val ? __expf(sc[2][kk] - m2) * i2 : 0.f;
        float a3 = val ? __expf(sc[3][kk] - m3) * i3 : 0.f;
        sc[0][kk] = a0; sc[1][kk] = a1; sc[2][kk] = a2; sc[3][kk] = a3;
        amean[((size_t)(b * NS + qrow)) * NS + kk] = 0.25f * (a0 + a1 + a2 + a3);
    }
    __syncthreads();

    // out[b, qrow, h*16+d] = sum_k att[h][k] * v[b,h,k,d]
    {
        int oi = t & 63, kg = t >> 6;
        int h = oi >> 4, d = oi & 15;
        float acc = 0.f;
        int kend = min((kg + 1) * 256, klim);
        for (int kk = kg * 256; kk < kend; ++kk)
            acc += sc[h][kk] * v[(((size_t)(b * NHEADS + h)) * NS + kk) * NDH + d];
        po[kg][oi] = acc;
    }
    __syncthreads();
    if (t < 64) {
        float r = po[0][t] + po[1][t] + po[2][t] + po[3][t];
        out[((size_t)(b * NS + qrow)) * NHID + t] = r;
    }
}

// ---------------------------------------------------------------------------
// Kernel 3: residual + LN1 + FFN(GELU exact) + residual + LN2, fused per row.
// One wave = one row; 4 rows per 256-thread block. W1/W2 transposed in LDS.
// ---------------------------------------------------------------------------
__device__ __forceinline__ float wsum(float v) {
    #pragma unroll
    for (int o = 32; o > 0; o >>= 1) v += __shfl_xor(v, o, 64);
    return v;
}

__global__ __launch_bounds__(256) void ffn_kernel(
    const float* __restrict__ x, const float* __restrict__ aout,
    const float* __restrict__ W1, const float* __restrict__ b1,
    const float* __restrict__ W2, const float* __restrict__ b2,
    const float* __restrict__ g1, const float* __restrict__ be1,
    const float* __restrict__ g2, const float* __restrict__ be2,
    float* __restrict__ y)
{
    __shared__ float w1t[64][65], w2t[64][65];
    __shared__ float n1sh[4][64], h1sh[4][64];
    int t = threadIdx.x;
    for (int i = t; i < 4096; i += 256) {
        int c = i >> 6, j = i & 63;
        w1t[j][c] = W1[i];
        w2t[j][c] = W2[i];
    }
    __syncthreads();
    int wv = t >> 6, d = t & 63;
    size_t row = (size_t)blockIdx.x * 4 + wv;

    float o1 = x[row * 64 + d] + aout[row * 64 + d];
    // LN1
    float mu = wsum(o1) * (1.f / 64.f);
    float diff = o1 - mu;
    float var = wsum(diff * diff) * (1.f / 64.f);
    float n1 = diff * rsqrtf(var + LN_EPS) * g1[d] + be1[d];
    n1sh[wv][d] = n1;
    __syncthreads();
    // h1 = gelu(n1 @ W1^T + b1)
    float acc = b1[d];
    #pragma unroll
    for (int j = 0; j < 64; ++j) acc = fmaf(n1sh[wv][j], w1t[j][d], acc);
    float ge = 0.5f * acc * (1.f + erff(acc * 0.70710678118654752f));
    h1sh[wv][d] = ge;
    __syncthreads();
    // ff = h1 @ W2^T + b2
    float acc2 = b2[d];
    #pragma unroll
    for (int j = 0; j < 64; ++j) acc2 = fmaf(h1sh[wv][j], w2t[j][d], acc2);
    float z = n1 + acc2;
    // LN2
    float mu2 = wsum(z) * (1.f / 64.f);
    float d2 = z - mu2;
    float var2 = wsum(d2 * d2) * (1.f / 64.f);
    float yv = d2 * rsqrtf(var2 + LN_EPS) * g2[d] + be2[d];
    y[row * 64 + d] = yv;
}

// ---------------------------------------------------------------------------
extern "C" void kernel_launch(void* const* d_in, const int* in_sizes, int n_in,
                              void* d_out, int out_size, void* d_ws, size_t ws_size,
                              hipStream_t stream) {
    const float* x   = (const float*)d_in[0];
    const int* lengths = (const int*)d_in[1];
    const float* Wq  = (const float*)d_in[3];
    const float* bq  = (const float*)d_in[4];
    const float* Wk  = (const float*)d_in[5];
    const float* bk  = (const float*)d_in[6];
    const float* Wv  = (const float*)d_in[7];
    const float* bv  = (const float*)d_in[8];
    const float* W1  = (const float*)d_in[9];
    const float* b1  = (const float*)d_in[10];
    const float* W2  = (const float*)d_in[11];
    const float* b2  = (const float*)d_in[12];
    const float* g1  = (const float*)d_in[13];
    const float* be1 = (const float*)d_in[14];
    const float* g2  = (const float*)d_in[15];
    const float* be2 = (const float*)d_in[16];

    float* y     = (float*)d_out;                       // [B,S,64]
    float* amean = y + (size_t)NB * NS * NHID;          // [B,S,S]

    float* qw   = (float*)d_ws;                         // [B,NH,S,DH]
    float* kw   = qw + (size_t)NB * NHEADS * NS * NDH;
    float* vw   = kw + (size_t)NB * NHEADS * NS * NDH;
    float* aoutw = vw + (size_t)NB * NHEADS * NS * NDH; // [B,S,64]

    hipLaunchKernelGGL(qkv_kernel, dim3(NB * NS / 32), dim3(256), 0, stream,
                       x, Wq, bq, Wk, bk, Wv, bv, qw, kw, vw);
    hipLaunchKernelGGL(attn_kernel, dim3(NS, NB), dim3(256), 0, stream,
                       qw, kw, vw, lengths, amean, aoutw);
    hipLaunchKernelGGL(ffn_kernel, dim3(NB * NS / 4), dim3(256), 0, stream,
                       x, aoutw, W1, b1, W2, b2, g1, be1, g2, be2, y);
}

// Round 3
// 190.956 us; speedup vs baseline: 1.3774x; 1.3774x over previous
//
#include <hip/hip_runtime.h>

#define NB 16
#define NS 1024
#define NHID 64
#define NHEADS 4
#define NDH 16
#define LN_EPS 1e-5f
#define TQ 32

// ---------------------------------------------------------------------------
// Kernel 1: QKV projection (unchanged).
// ---------------------------------------------------------------------------
__global__ __launch_bounds__(256) void qkv_kernel(
    const float* __restrict__ x,
    const float* __restrict__ Wq, const float* __restrict__ bq,
    const float* __restrict__ Wk, const float* __restrict__ bk,
    const float* __restrict__ Wv, const float* __restrict__ bv,
    float* __restrict__ qo, float* __restrict__ ko, float* __restrict__ vo)
{
    __shared__ float wqt[64][65], wkt[64][65], wvt[64][65];
    __shared__ float xs[32][64];
    int t = threadIdx.x;
    int row0 = blockIdx.x * 32;
    for (int i = t; i < 4096; i += 256) {
        int c = i >> 6, j = i & 63;
        wqt[j][c] = Wq[i];
        wkt[j][c] = Wk[i];
        wvt[j][c] = Wv[i];
    }
    for (int i = t; i < 2048; i += 256) {
        xs[i >> 6][i & 63] = x[(size_t)row0 * 64 + i];
    }
    __syncthreads();
    int c = t & 63, rq = t >> 6;
    int h = c >> 4, d = c & 15;
    float bqv = bq[c], bkv = bk[c], bvv = bv[c];
    for (int rr = 0; rr < 8; ++rr) {
        int r = rq * 8 + rr;
        float aq = bqv, ak = bkv, av = bvv;
        #pragma unroll
        for (int j = 0; j < 64; ++j) {
            float xv = xs[r][j];
            aq = fmaf(xv, wqt[j][c], aq);
            ak = fmaf(xv, wkt[j][c], ak);
            av = fmaf(xv, wvt[j][c], av);
        }
        int srow = row0 + r;
        int b_ = srow >> 10, s_ = srow & 1023;
        size_t o = (((size_t)(b_ * NHEADS + h)) * NS + s_) * NDH + d;
        qo[o] = aq; ko[o] = ak; vo[o] = av;
    }
}

// ---------------------------------------------------------------------------
// Kernel 2: q-tiled attention. Block = (b, 32 q-rows). Lane = (head-pair, q-row).
// FIX vs round 2: mask must include q-row validity — a padded row (qrow >= len)
// is fully masked in the reference (softmax*mask -> exact zeros). valid =
// (qrow < len) && (kg <= qrow); this also implies kg < len.
// ---------------------------------------------------------------------------
__global__ __launch_bounds__(256, 2) void attn2_kernel(
    const float* __restrict__ q, const float* __restrict__ k,
    const float* __restrict__ v, const int* __restrict__ lengths,
    float* __restrict__ amean,   // [B,S,S]
    float* __restrict__ out)     // [B,S,64]
{
    __shared__ float Klds[64][68];
    __shared__ float Vlds[64][68];
    __shared__ float alds[TQ][65];
    __shared__ float obuf[2][TQ][65];
    __shared__ float zlds[4][64][2];

    const int t  = threadIdx.x;
    const int wv = t >> 6, ln = t & 63;
    const int hp = ln >> 5, ql = ln & 31;
    const int q0 = blockIdx.x * TQ;
    const int b  = blockIdx.y;
    const int len  = lengths[b];
    const int qrow = q0 + ql;
    const bool qvalid = qrow < len;

    float4 qv[2][4];
    #pragma unroll
    for (int e = 0; e < 2; ++e) {
        const float4* qp = (const float4*)
            &q[(((size_t)(b * NHEADS + hp * 2 + e)) * NS + qrow) * NDH];
        qv[e][0] = qp[0]; qv[e][1] = qp[1]; qv[e][2] = qp[2]; qv[e][3] = qp[3];
    }

    const int nk = (len <= q0) ? 0 : min(q0 + TQ, len);
    const int ntiles = (nk + 63) >> 6;
    const int kkb = wv << 4;

    // ------------------- pass 1: Z = sum exp(score) -------------------
    float Z0 = 0.f, Z1 = 0.f;
    for (int tile = 0; tile < ntiles; ++tile) {
        const int k0 = tile << 6;
        #pragma unroll
        for (int i = 0; i < 4; ++i) {
            int idx = t + 256 * i, kk = idx & 63, j4 = idx >> 6;
            *(float4*)&Klds[kk][j4 * 4] = *(const float4*)
                &k[(((size_t)(b * NHEADS + (j4 >> 2))) * NS + k0 + kk) * NDH + (j4 & 3) * 4];
        }
        __syncthreads();
        #pragma unroll 4
        for (int kki = 0; kki < 16; ++kki) {
            const int kk = kkb + kki, kg = k0 + kk;
            const bool valid = qvalid && (kg <= qrow);
            const float4* rk = (const float4*)&Klds[kk][0];
            float s0 = 0.f, s1 = 0.f;
            #pragma unroll
            for (int i = 0; i < 4; ++i) {
                float4 ka = rk[hp * 8 + i], kb2 = rk[hp * 8 + 4 + i];
                s0 = fmaf(ka.x, qv[0][i].x, s0); s0 = fmaf(ka.y, qv[0][i].y, s0);
                s0 = fmaf(ka.z, qv[0][i].z, s0); s0 = fmaf(ka.w, qv[0][i].w, s0);
                s1 = fmaf(kb2.x, qv[1][i].x, s1); s1 = fmaf(kb2.y, qv[1][i].y, s1);
                s1 = fmaf(kb2.z, qv[1][i].z, s1); s1 = fmaf(kb2.w, qv[1][i].w, s1);
            }
            Z0 += valid ? __expf(s0 * 0.125f) : 0.f;
            Z1 += valid ? __expf(s1 * 0.125f) : 0.f;
        }
        __syncthreads();
    }
    zlds[wv][ln][0] = Z0;
    zlds[wv][ln][1] = Z1;
    __syncthreads();
    const float zt0 = zlds[0][ln][0] + zlds[1][ln][0] + zlds[2][ln][0] + zlds[3][ln][0];
    const float zt1 = zlds[0][ln][1] + zlds[1][ln][1] + zlds[2][ln][1] + zlds[3][ln][1];
    const float iz0 = (zt0 > 0.f) ? 1.f / zt0 : 0.f;
    const float iz1 = (zt1 > 0.f) ? 1.f / zt1 : 0.f;
    __syncthreads();

    // ------------------- pass 2: probs, amean, PV -------------------
    float4 o4[2][4];
    #pragma unroll
    for (int e = 0; e < 2; ++e)
        #pragma unroll
        for (int i = 0; i < 4; ++i) o4[e][i] = make_float4(0.f, 0.f, 0.f, 0.f);

    for (int tile = 0; tile < ntiles; ++tile) {
        const int k0 = tile << 6;
        #pragma unroll
        for (int i = 0; i < 4; ++i) {
            int idx = t + 256 * i, kk = idx & 63, j4 = idx >> 6;
            size_t goff = (((size_t)(b * NHEADS + (j4 >> 2))) * NS + k0 + kk) * NDH + (j4 & 3) * 4;
            *(float4*)&Klds[kk][j4 * 4] = *(const float4*)&k[goff];
            *(float4*)&Vlds[kk][j4 * 4] = *(const float4*)&v[goff];
        }
        if (tile > 0) {
            const int kp = (tile - 1) << 6;
            #pragma unroll
            for (int i = 0; i < 2; ++i) {
                int idx = t + 256 * i, r = idx >> 4, c4 = idx & 15;
                float4 w4 = make_float4(alds[r][c4 * 4], alds[r][c4 * 4 + 1],
                                        alds[r][c4 * 4 + 2], alds[r][c4 * 4 + 3]);
                *(float4*)&amean[((size_t)(b * NS + q0 + r)) * NS + kp + c4 * 4] = w4;
            }
        }
        __syncthreads();
        #pragma unroll 4
        for (int kki = 0; kki < 16; ++kki) {
            const int kk = kkb + kki, kg = k0 + kk;
            const bool valid = qvalid && (kg <= qrow);
            const float4* rk = (const float4*)&Klds[kk][0];
            float s0 = 0.f, s1 = 0.f;
            #pragma unroll
            for (int i = 0; i < 4; ++i) {
                float4 ka = rk[hp * 8 + i], kb2 = rk[hp * 8 + 4 + i];
                s0 = fmaf(ka.x, qv[0][i].x, s0); s0 = fmaf(ka.y, qv[0][i].y, s0);
                s0 = fmaf(ka.z, qv[0][i].z, s0); s0 = fmaf(ka.w, qv[0][i].w, s0);
                s1 = fmaf(kb2.x, qv[1][i].x, s1); s1 = fmaf(kb2.y, qv[1][i].y, s1);
                s1 = fmaf(kb2.z, qv[1][i].z, s1); s1 = fmaf(kb2.w, qv[1][i].w, s1);
            }
            const float pe0 = valid ? __expf(s0 * 0.125f) : 0.f;
            const float pe1 = valid ? __expf(s1 * 0.125f) : 0.f;
            const float p0 = pe0 * iz0, p1 = pe1 * iz1;
            float asum = p0 + p1;
            const float aoth = __shfl_xor(asum, 32);
            if (hp == 0) alds[ql][kk] = 0.25f * (asum + aoth);
            const float4* rv = (const float4*)&Vlds[kk][0];
            #pragma unroll
            for (int i = 0; i < 4; ++i) {
                float4 va = rv[hp * 8 + i], vb = rv[hp * 8 + 4 + i];
                o4[0][i].x = fmaf(p0, va.x, o4[0][i].x);
                o4[0][i].y = fmaf(p0, va.y, o4[0][i].y);
                o4[0][i].z = fmaf(p0, va.z, o4[0][i].z);
                o4[0][i].w = fmaf(p0, va.w, o4[0][i].w);
                o4[1][i].x = fmaf(p1, vb.x, o4[1][i].x);
                o4[1][i].y = fmaf(p1, vb.y, o4[1][i].y);
                o4[1][i].z = fmaf(p1, vb.z, o4[1][i].z);
                o4[1][i].w = fmaf(p1, vb.w, o4[1][i].w);
            }
        }
        __syncthreads();
    }

    if (ntiles > 0) {
        const int kp = (ntiles - 1) << 6;
        #pragma unroll
        for (int i = 0; i < 2; ++i) {
            int idx = t + 256 * i, r = idx >> 4, c4 = idx & 15;
            float4 w4 = make_float4(alds[r][c4 * 4], alds[r][c4 * 4 + 1],
                                    alds[r][c4 * 4 + 2], alds[r][c4 * 4 + 3]);
            *(float4*)&amean[((size_t)(b * NS + q0 + r)) * NS + kp + c4 * 4] = w4;
        }
    }

    if (wv < 2) {
        #pragma unroll
        for (int e = 0; e < 2; ++e)
            #pragma unroll
            for (int i = 0; i < 4; ++i) {
                int j = hp * 32 + e * 16 + i * 4;
                obuf[wv][ql][j + 0] = o4[e][i].x;
                obuf[wv][ql][j + 1] = o4[e][i].y;
                obuf[wv][ql][j + 2] = o4[e][i].z;
                obuf[wv][ql][j + 3] = o4[e][i].w;
            }
    }
    __syncthreads();
    if (wv >= 2) {
        #pragma unroll
        for (int e = 0; e < 2; ++e)
            #pragma unroll
            for (int i = 0; i < 4; ++i) {
                int j = hp * 32 + e * 16 + i * 4;
                obuf[wv - 2][ql][j + 0] += o4[e][i].x;
                obuf[wv - 2][ql][j + 1] += o4[e][i].y;
                obuf[wv - 2][ql][j + 2] += o4[e][i].z;
                obuf[wv - 2][ql][j + 3] += o4[e][i].w;
            }
    }
    __syncthreads();
    #pragma unroll
    for (int i = 0; i < 2; ++i) {
        int idx = t + 256 * i, r = idx >> 4, c4 = idx & 15;
        float4 w4;
        w4.x = obuf[0][r][c4 * 4 + 0] + obuf[1][r][c4 * 4 + 0];
        w4.y = obuf[0][r][c4 * 4 + 1] + obuf[1][r][c4 * 4 + 1];
        w4.z = obuf[0][r][c4 * 4 + 2] + obuf[1][r][c4 * 4 + 2];
        w4.w = obuf[0][r][c4 * 4 + 3] + obuf[1][r][c4 * 4 + 3];
        *(float4*)&out[((size_t)(b * NS + q0 + r)) * NHID + c4 * 4] = w4;
    }

    const int kz = ntiles << 6;
    const int nz4 = (NS - kz) >> 2;
    const float4 z4 = make_float4(0.f, 0.f, 0.f, 0.f);
    for (int r = 0; r < TQ; ++r) {
        for (int c4 = t; c4 < nz4; c4 += 256) {
            *(float4*)&amean[((size_t)(b * NS + q0 + r)) * NS + kz + c4 * 4] = z4;
        }
    }
}

// ---------------------------------------------------------------------------
// Kernel 3: residual + LN1 + FFN(GELU exact) + residual + LN2 (unchanged).
// ---------------------------------------------------------------------------
__device__ __forceinline__ float wsum(float v) {
    #pragma unroll
    for (int o = 32; o > 0; o >>= 1) v += __shfl_xor(v, o, 64);
    return v;
}

__global__ __launch_bounds__(256) void ffn_kernel(
    const float* __restrict__ x, const float* __restrict__ aout,
    const float* __restrict__ W1, const float* __restrict__ b1,
    const float* __restrict__ W2, const float* __restrict__ b2,
    const float* __restrict__ g1, const float* __restrict__ be1,
    const float* __restrict__ g2, const float* __restrict__ be2,
    float* __restrict__ y)
{
    __shared__ float w1t[64][65], w2t[64][65];
    __shared__ float n1sh[4][64], h1sh[4][64];
    int t = threadIdx.x;
    for (int i = t; i < 4096; i += 256) {
        int c = i >> 6, j = i & 63;
        w1t[j][c] = W1[i];
        w2t[j][c] = W2[i];
    }
    __syncthreads();
    int wv = t >> 6, d = t & 63;
    size_t row = (size_t)blockIdx.x * 4 + wv;

    float o1 = x[row * 64 + d] + aout[row * 64 + d];
    float mu = wsum(o1) * (1.f / 64.f);
    float diff = o1 - mu;
    float var = wsum(diff * diff) * (1.f / 64.f);
    float n1 = diff * rsqrtf(var + LN_EPS) * g1[d] + be1[d];
    n1sh[wv][d] = n1;
    __syncthreads();
    float acc = b1[d];
    #pragma unroll
    for (int j = 0; j < 64; ++j) acc = fmaf(n1sh[wv][j], w1t[j][d], acc);
    float ge = 0.5f * acc * (1.f + erff(acc * 0.70710678118654752f));
    h1sh[wv][d] = ge;
    __syncthreads();
    float acc2 = b2[d];
    #pragma unroll
    for (int j = 0; j < 64; ++j) acc2 = fmaf(h1sh[wv][j], w2t[j][d], acc2);
    float z = n1 + acc2;
    float mu2 = wsum(z) * (1.f / 64.f);
    float d2 = z - mu2;
    float var2 = wsum(d2 * d2) * (1.f / 64.f);
    float yv = d2 * rsqrtf(var2 + LN_EPS) * g2[d] + be2[d];
    y[row * 64 + d] = yv;
}

// ---------------------------------------------------------------------------
extern "C" void kernel_launch(void* const* d_in, const int* in_sizes, int n_in,
                              void* d_out, int out_size, void* d_ws, size_t ws_size,
                              hipStream_t stream) {
    const float* x   = (const float*)d_in[0];
    const int* lengths = (const int*)d_in[1];
    const float* Wq  = (const float*)d_in[3];
    const float* bq  = (const float*)d_in[4];
    const float* Wk  = (const float*)d_in[5];
    const float* bk  = (const float*)d_in[6];
    const float* Wv  = (const float*)d_in[7];
    const float* bv  = (const float*)d_in[8];
    const float* W1  = (const float*)d_in[9];
    const float* b1  = (const float*)d_in[10];
    const float* W2  = (const float*)d_in[11];
    const float* b2  = (const float*)d_in[12];
    const float* g1  = (const float*)d_in[13];
    const float* be1 = (const float*)d_in[14];
    const float* g2  = (const float*)d_in[15];
    const float* be2 = (const float*)d_in[16];

    float* y     = (float*)d_out;                       // [B,S,64]
    float* amean = y + (size_t)NB * NS * NHID;          // [B,S,S]

    float* qw    = (float*)d_ws;                        // [B,NH,S,DH]
    float* kw    = qw + (size_t)NB * NHEADS * NS * NDH;
    float* vw    = kw + (size_t)NB * NHEADS * NS * NDH;
    float* aoutw = vw + (size_t)NB * NHEADS * NS * NDH; // [B,S,64]

    hipLaunchKernelGGL(qkv_kernel, dim3(NB * NS / 32), dim3(256), 0, stream,
                       x, Wq, bq, Wk, bk, Wv, bv, qw, kw, vw);
    hipLaunchKernelGGL(attn2_kernel, dim3(NS / TQ, NB), dim3(256), 0, stream,
                       qw, kw, vw, lengths, amean, aoutw);
    hipLaunchKernelGGL(ffn_kernel, dim3(NB * NS / 4), dim3(256), 0, stream,
                       x, aoutw, W1, b1, W2, b2, g1, be1, g2, be2, y);
}